// Round 8
// baseline (185.380 us; speedup 1.0000x reference)
//
#include <hip/hip_runtime.h>

// EmbeddedLogRegClassifier: fused gather-pool + logreg head.
// pooled[b, d]   = (1/L) * sum_{v,l} emb[diag_idx[b,v,l], d]
// pooled[b, D+d] = (1/L) * sum_{v,l} emb[proc_idx[b,v,l], d]
// out[b, c]      = bias[c] + sum_k pooled[b, k] * W[c, k]
//
// R8: wave-per-(sample, half, slice) gather — no barriers, no LDS, no atomics.
//   k1 prep:   emb fp32 -> fp16 into XCD-sliced [8][12501][128] (row 12500 of
//              each slice = zeros, sentinel) + per-sample counting-sort of
//              indices by slice (compact u16 lists + offsets).
//   k2 slice:  4 independent waves per block (all same slice -> bid&7 XCD
//              pinning). Each wave: read its list segment from global
//              (16-lane broadcast), gather 4 rows/iter via dwordx4 from the
//              3.2 MB L2-resident slice, pk_add_f16, shfl_xor reduce,
//              one dense uint4 store per half into pooledp[b][h][slice].
//   k3 head:   sum 8 slice partials (fp16) -> x, then out = x @ W^T + b.

typedef _Float16 h2 __attribute__((ext_vector_type(2)));

constexpr int B      = 2048;
constexpr int V      = 50;
constexpr int L      = 20;
constexpr int D      = 128;
constexpr int NIDX   = V * L;     // 1000 indices per (sample, half)
constexpr int NCLASS = 128;
constexpr int TWO_D  = 2 * D;     // 256
constexpr int VOCAB  = 100000;
constexpr int NSLICE = 8;
constexpr int SLICE_ROWS = VOCAB / NSLICE;          // 12500
constexpr int SROWS_P    = SLICE_ROWS + 1;          // +1 zero row (sentinel)

__device__ __forceinline__ unsigned short f2bf_rne(float f) {
    unsigned int u = __float_as_uint(f);
    unsigned int r = (u + 0x7FFFu + ((u >> 16) & 1u)) >> 16;
    return (unsigned short)r;
}
__device__ __forceinline__ float uif(unsigned int u) { return __uint_as_float(u); }

__device__ __forceinline__ unsigned int pk_f16(float a, float b) {
    return __builtin_bit_cast(unsigned int, __builtin_amdgcn_cvt_pkrtz(a, b));
}
__device__ __forceinline__ h2 h2_shfl_xor(h2 a, int m) {
    return __builtin_bit_cast(h2, __shfl_xor(__builtin_bit_cast(int, a), m, 64));
}

// ---------------- k1: fused convert + zero-rows + bucket --------------------
// grid = 12500 (convert) + 1 (zero rows) + 2048 (bucket) blocks of 256.
__global__ __launch_bounds__(256)
void prep_kernel(const float* __restrict__ emb,
                 const int* __restrict__ diag_idx,
                 const int* __restrict__ proc_idx,
                 unsigned short* __restrict__ embb,   // fp16 [8][12501][128]
                 unsigned short* __restrict__ sorted, // [B][2][1000] compact
                 int* __restrict__ offs)              // [B][2][9]
{
    const int bid = blockIdx.x;
    const int tid = threadIdx.x;

    if (bid < 12500) {
        // convert: one float4 -> one uint2 (4 fp16) per thread
        const int i4 = bid * 256 + tid;          // [0, 3.2M) 8B-units
        const int r  = i4 >> 5;                  // 32 units per row
        const int s  = r / SLICE_ROWS;
        const float4 v = reinterpret_cast<const float4*>(emb)[i4];
        uint2 o;
        o.x = pk_f16(v.x, v.y);
        o.y = pk_f16(v.z, v.w);
        reinterpret_cast<uint2*>(embb)[i4 + s * 32] = o;  // sliced layout
        return;
    }
    if (bid == 12500) {
        // zero row 12500 of each slice: 8 rows x 32 uint2
        const int s = tid >> 5, u = tid & 31;
        reinterpret_cast<uint2*>(embb)[((size_t)s * SROWS_P + SLICE_ROWS) * 32 + u] =
            make_uint2(0u, 0u);
        return;
    }

    // bucket: one sample per block
    const int b = bid - 12501;

    __shared__ int cnt[2][NSLICE];
    __shared__ int woff[2][NSLICE];
    __shared__ int offsS[2][NSLICE + 1];
    __shared__ unsigned short sl[2][NIDX];

    if (tid < 16) cnt[tid >> 3][tid & 7] = 0;
    __syncthreads();

    int4 qd = make_int4(0, 0, 0, 0), qp = make_int4(0, 0, 0, 0);
    const bool act = tid < NIDX / 4;
    if (act) {
        qd = reinterpret_cast<const int4*>(diag_idx + (size_t)b * NIDX)[tid];
        qp = reinterpret_cast<const int4*>(proc_idx + (size_t)b * NIDX)[tid];
        atomicAdd(&cnt[0][qd.x / SLICE_ROWS], 1);
        atomicAdd(&cnt[0][qd.y / SLICE_ROWS], 1);
        atomicAdd(&cnt[0][qd.z / SLICE_ROWS], 1);
        atomicAdd(&cnt[0][qd.w / SLICE_ROWS], 1);
        atomicAdd(&cnt[1][qp.x / SLICE_ROWS], 1);
        atomicAdd(&cnt[1][qp.y / SLICE_ROWS], 1);
        atomicAdd(&cnt[1][qp.z / SLICE_ROWS], 1);
        atomicAdd(&cnt[1][qp.w / SLICE_ROWS], 1);
    }
    __syncthreads();

    if (tid < 2) {
        int run = 0;
        for (int k = 0; k < NSLICE; ++k) {
            offsS[tid][k] = run;
            woff[tid][k]  = run;
            run += cnt[tid][k];
        }
        offsS[tid][NSLICE] = run;   // == 1000
    }
    __syncthreads();

    if (act) {
        int s, p;
        s = qd.x / SLICE_ROWS; p = atomicAdd(&woff[0][s], 1); sl[0][p] = (unsigned short)(qd.x - s * SLICE_ROWS);
        s = qd.y / SLICE_ROWS; p = atomicAdd(&woff[0][s], 1); sl[0][p] = (unsigned short)(qd.y - s * SLICE_ROWS);
        s = qd.z / SLICE_ROWS; p = atomicAdd(&woff[0][s], 1); sl[0][p] = (unsigned short)(qd.z - s * SLICE_ROWS);
        s = qd.w / SLICE_ROWS; p = atomicAdd(&woff[0][s], 1); sl[0][p] = (unsigned short)(qd.w - s * SLICE_ROWS);
        s = qp.x / SLICE_ROWS; p = atomicAdd(&woff[1][s], 1); sl[1][p] = (unsigned short)(qp.x - s * SLICE_ROWS);
        s = qp.y / SLICE_ROWS; p = atomicAdd(&woff[1][s], 1); sl[1][p] = (unsigned short)(qp.y - s * SLICE_ROWS);
        s = qp.z / SLICE_ROWS; p = atomicAdd(&woff[1][s], 1); sl[1][p] = (unsigned short)(qp.z - s * SLICE_ROWS);
        s = qp.w / SLICE_ROWS; p = atomicAdd(&woff[1][s], 1); sl[1][p] = (unsigned short)(qp.w - s * SLICE_ROWS);
    }
    __syncthreads();

    unsigned int* so = reinterpret_cast<unsigned int*>(sorted + (size_t)b * 2 * NIDX);
    for (int t = tid; t < NIDX; t += 256) {           // 1000 u32 pairs
        const int h = t / (NIDX / 2), i = t % (NIDX / 2);
        so[t] = (unsigned int)sl[h][2 * i] | ((unsigned int)sl[h][2 * i + 1] << 16);
    }
    if (tid < 2 * (NSLICE + 1))
        offs[b * 2 * (NSLICE + 1) + tid] = offsS[tid / (NSLICE + 1)][tid % (NSLICE + 1)];
}

// ---------------- k2: wave-per-(sample, half, slice) gather -----------------
// grid = 8192 blocks of 256 (4 independent waves, all same slice).
// bid = bq*8 + slice; wave w -> sample bq*2 + (w>>1), half w&1.
__global__ __launch_bounds__(256, 6)
void slice_pool_kernel(const unsigned short* __restrict__ embb,
                       const unsigned short* __restrict__ sorted,
                       const int* __restrict__ offs,
                       unsigned int* __restrict__ pooledp)  // fp16x2 [B][2][8][64]
{
    const int bid  = blockIdx.x;
    const int s    = bid & (NSLICE - 1);     // consecutive bids -> XCDs
    const int bq   = bid >> 3;
    const int tid  = threadIdx.x;
    const int wave = tid >> 6;
    const int lane = tid & 63;
    const int b    = bq * 2 + (wave >> 1);
    const int h    = wave & 1;

    const int* ob  = offs + (b * 2 + h) * (NSLICE + 1);
    const int beg  = ob[s];
    const int n    = ob[s + 1] - beg;

    const unsigned short* __restrict__ lst =
        sorted + (size_t)(b * 2 + h) * NIDX + beg;
    const uint4* __restrict__ sbase =
        reinterpret_cast<const uint4*>(embb + (size_t)s * SROWS_P * D);

    const int sub = lane >> 4;          // which of 4 rows in the batch
    const int c   = lane & 15;          // 16B chunk within the row

    // 4 rows/iter: 16-lane groups broadcast-load the row id, then dwordx4.
    // Tail rows select the zero sentinel row via cndmask.
    h2 a0 = {0, 0}, a1 = {0, 0}, a2 = {0, 0}, a3 = {0, 0};
    #pragma unroll 8
    for (int i = 0; i < n; i += 4) {
        const int j  = i + sub;
        const int rv = (int)lst[j];                    // may over-read <=3 (padded)
        const int rl = (j < n) ? rv : SLICE_ROWS;      // sentinel -> zeros
        const uint4 e = sbase[rl * 16 + c];
        a0 += __builtin_bit_cast(h2, e.x);             // v_pk_add_f16
        a1 += __builtin_bit_cast(h2, e.y);
        a2 += __builtin_bit_cast(h2, e.z);
        a3 += __builtin_bit_cast(h2, e.w);
    }

    // reduce across the 4 sub-groups (lanes c, c+16, c+32, c+48)
    a0 += h2_shfl_xor(a0, 16); a1 += h2_shfl_xor(a1, 16);
    a2 += h2_shfl_xor(a2, 16); a3 += h2_shfl_xor(a3, 16);
    a0 += h2_shfl_xor(a0, 32); a1 += h2_shfl_xor(a1, 32);
    a2 += h2_shfl_xor(a2, 32); a3 += h2_shfl_xor(a3, 32);

    if (lane < 16) {
        uint4 o;
        o.x = __builtin_bit_cast(unsigned int, a0);
        o.y = __builtin_bit_cast(unsigned int, a1);
        o.z = __builtin_bit_cast(unsigned int, a2);
        o.w = __builtin_bit_cast(unsigned int, a3);
        // dense 256B store per (b, h, s): lanes 0-15 x 16B
        reinterpret_cast<uint4*>(pooledp + ((size_t)((b * 2 + h) * NSLICE + s) * 64))[c] = o;
    }
}

// ---------------- k3: head — sum slice partials + logreg --------------------
__global__ __launch_bounds__(128)
void head_kernel(const unsigned int* __restrict__ pooledp,
                 const float* __restrict__ W,
                 const float* __restrict__ bias,
                 float* __restrict__ out)
{
    __shared__ float x[TWO_D];
    const int b   = blockIdx.x;
    const int tid = threadIdx.x;
    const int h   = tid >> 6;           // 0 diag, 1 proc
    const int c2  = tid & 63;           // dword index = dim pair

    const unsigned int* pp = pooledp + (size_t)(b * 2 + h) * NSLICE * 64 + c2;
    float sx = 0.f, sy = 0.f;
    #pragma unroll
    for (int sl = 0; sl < NSLICE; ++sl) {
        const h2 v = __builtin_bit_cast(h2, pp[sl * 64]);
        sx += (float)v.x;
        sy += (float)v.y;
    }
    x[h * D + 2 * c2]     = sx * (1.0f / L);
    x[h * D + 2 * c2 + 1] = sy * (1.0f / L);
    __syncthreads();

    const float4* __restrict__ wrow =
        reinterpret_cast<const float4*>(W + (size_t)tid * TWO_D);
    const float4* __restrict__ xv = reinterpret_cast<const float4*>(x);
    float acc = bias[tid];
    #pragma unroll 16
    for (int k = 0; k < TWO_D / 4; ++k) {
        const float4 w4 = wrow[k];
        const float4 x4 = xv[k];
        acc = fmaf(w4.x, x4.x, acc);
        acc = fmaf(w4.y, x4.y, acc);
        acc = fmaf(w4.z, x4.z, acc);
        acc = fmaf(w4.w, x4.w, acc);
    }
    out[(size_t)b * NCLASS + tid] = acc;
}

// ---------------- fallbacks (ws too small) ----------------------------------
__global__ __launch_bounds__(256)
void convert_flat_kernel(const float* __restrict__ emb, unsigned short* __restrict__ o)
{
    const int i = blockIdx.x * 256 + threadIdx.x;
    const float4 v = reinterpret_cast<const float4*>(emb)[i];
    ushort4 u;
    u.x = f2bf_rne(v.x); u.y = f2bf_rne(v.y);
    u.z = f2bf_rne(v.z); u.w = f2bf_rne(v.w);
    reinterpret_cast<ushort4*>(o)[i] = u;
}

__global__ __launch_bounds__(256, 4)
void pool_gemm_bf16_kernel(const int* __restrict__ diag_idx,
                           const int* __restrict__ proc_idx,
                           const unsigned short* __restrict__ embb,
                           const float* __restrict__ W,
                           const float* __restrict__ bias,
                           float* __restrict__ out)
{
    __shared__ float4 part4[4][64];
    __shared__ float  x_lds[TWO_D];

    const int b    = blockIdx.x;
    const int tid  = threadIdx.x;
    const int wave = tid >> 6;
    const int lane = tid & 63;

    const int half  = wave >> 1;
    const int chunk = wave & 1;
    const int* __restrict__ idx =
        (half == 0 ? diag_idx : proc_idx) + (size_t)b * NIDX + (size_t)chunk * (NIDX / 2);
    const int2* __restrict__ idx2 = reinterpret_cast<const int2*>(idx);

    const ushort4* __restrict__ emb4 = reinterpret_cast<const ushort4*>(embb);
    const int c = lane & 31;

    float4 acc = make_float4(0.f, 0.f, 0.f, 0.f);
    #pragma unroll 10
    for (int i = 0; i < NIDX / 4; ++i) {
        const int2 p = idx2[i];
        const int  r = (lane & 32) ? p.y : p.x;
        const ushort4 e = emb4[(size_t)r * (D / 4) + c];
        acc.x += uif((unsigned int)e.x << 16);
        acc.y += uif((unsigned int)e.y << 16);
        acc.z += uif((unsigned int)e.z << 16);
        acc.w += uif((unsigned int)e.w << 16);
    }
    part4[wave][lane] = acc;
    __syncthreads();

    {
        const int h   = tid >> 7;
        const int rem = tid & 127;
        const int cc  = rem >> 2;
        const int j   = rem & 3;
        const float* p0 = reinterpret_cast<const float*>(&part4[2 * h][cc]);
        const float* p1 = reinterpret_cast<const float*>(&part4[2 * h][cc + 32]);
        const float* p2 = reinterpret_cast<const float*>(&part4[2 * h + 1][cc]);
        const float* p3 = reinterpret_cast<const float*>(&part4[2 * h + 1][cc + 32]);
        x_lds[tid] = (p0[j] + p1[j] + p2[j] + p3[j]) * (1.0f / L);
    }
    __syncthreads();

    if (tid < NCLASS) {
        const float4* __restrict__ wrow =
            reinterpret_cast<const float4*>(W + (size_t)tid * TWO_D);
        const float4* __restrict__ xv = reinterpret_cast<const float4*>(x_lds);
        float s = bias[tid];
        #pragma unroll 8
        for (int k = 0; k < TWO_D / 4; ++k) {
            const float4 w4 = wrow[k];
            const float4 x4 = xv[k];
            s = fmaf(w4.x, x4.x, s);
            s = fmaf(w4.y, x4.y, s);
            s = fmaf(w4.z, x4.z, s);
            s = fmaf(w4.w, x4.w, s);
        }
        out[(size_t)b * NCLASS + tid] = s;
    }
}

__global__ __launch_bounds__(256, 4)
void pool_gemm_f32_kernel(const int* __restrict__ diag_idx,
                          const int* __restrict__ proc_idx,
                          const float* __restrict__ emb,
                          const float* __restrict__ W,
                          const float* __restrict__ bias,
                          float* __restrict__ out)
{
    __shared__ float4 part4[4][64];
    __shared__ float  x_lds[TWO_D];

    const int b    = blockIdx.x;
    const int tid  = threadIdx.x;
    const int wave = tid >> 6;
    const int lane = tid & 63;

    const int half  = wave >> 1;
    const int chunk = wave & 1;
    const int* __restrict__ idx =
        (half == 0 ? diag_idx : proc_idx) + (size_t)b * NIDX + (size_t)chunk * (NIDX / 2);
    const int2* __restrict__ idx2 = reinterpret_cast<const int2*>(idx);

    const float4* __restrict__ emb4 = reinterpret_cast<const float4*>(emb);
    const int c = lane & 31;

    float4 acc = make_float4(0.f, 0.f, 0.f, 0.f);
    #pragma unroll 5
    for (int i = 0; i < NIDX / 4; ++i) {
        const int2 p = idx2[i];
        const int  r = (lane & 32) ? p.y : p.x;
        const float4 e = emb4[(size_t)r * (D / 4) + c];
        acc.x += e.x; acc.y += e.y; acc.z += e.z; acc.w += e.w;
    }
    part4[wave][lane] = acc;
    __syncthreads();

    {
        const int h   = tid >> 7;
        const int rem = tid & 127;
        const int cc  = rem >> 2;
        const int j   = rem & 3;
        const float* p0 = reinterpret_cast<const float*>(&part4[2 * h][cc]);
        const float* p1 = reinterpret_cast<const float*>(&part4[2 * h][cc + 32]);
        const float* p2 = reinterpret_cast<const float*>(&part4[2 * h + 1][cc]);
        const float* p3 = reinterpret_cast<const float*>(&part4[2 * h + 1][cc + 32]);
        x_lds[tid] = (p0[j] + p1[j] + p2[j] + p3[j]) * (1.0f / L);
    }
    __syncthreads();

    if (tid < NCLASS) {
        const float4* __restrict__ wrow =
            reinterpret_cast<const float4*>(W + (size_t)tid * TWO_D);
        const float4* __restrict__ xv = reinterpret_cast<const float4*>(x_lds);
        float s = bias[tid];
        #pragma unroll 8
        for (int k = 0; k < TWO_D / 4; ++k) {
            const float4 w4 = wrow[k];
            const float4 x4 = xv[k];
            s = fmaf(w4.x, x4.x, s);
            s = fmaf(w4.y, x4.y, s);
            s = fmaf(w4.z, x4.z, s);
            s = fmaf(w4.w, x4.w, s);
        }
        out[(size_t)b * NCLASS + tid] = s;
    }
}

extern "C" void kernel_launch(void* const* d_in, const int* in_sizes, int n_in,
                              void* d_out, int out_size, void* d_ws, size_t ws_size,
                              hipStream_t stream)
{
    const int*   diag = (const int*)d_in[0];
    const int*   proc = (const int*)d_in[1];
    const float* emb  = (const float*)d_in[2];
    const float* W    = (const float*)d_in[3];
    const float* bias = (const float*)d_in[4];
    float*       out  = (float*)d_out;

    const size_t embb_bytes    = (size_t)NSLICE * SROWS_P * D * sizeof(unsigned short); // 25.602 MB
    const size_t sorted_bytes  = (size_t)B * 2 * NIDX * sizeof(unsigned short) + 16;    // 8.192 MB + pad
    const size_t offs_bytes    = (size_t)B * 2 * (NSLICE + 1) * sizeof(int);            // 147 KB
    const size_t pooledp_bytes = (size_t)B * 2 * NSLICE * 64 * sizeof(unsigned int);    // 8.39 MB
    const size_t need = embb_bytes + sorted_bytes + offs_bytes + pooledp_bytes;

    const size_t emb_flat_bytes = (size_t)VOCAB * D * sizeof(unsigned short);           // 25.6 MB

    if (ws_size >= need) {
        char* p = (char*)d_ws;
        unsigned short* embb    = (unsigned short*)p;             p += embb_bytes;
        unsigned short* sorted  = (unsigned short*)p;             p += sorted_bytes;
        int*            offs    = (int*)p;                        p += offs_bytes;
        unsigned int*   pooledp = (unsigned int*)p;

        prep_kernel<<<12501 + B, 256, 0, stream>>>(emb, diag, proc, embb, sorted, offs);
        slice_pool_kernel<<<(B / 2) * NSLICE, 256, 0, stream>>>(embb, sorted, offs, pooledp);
        head_kernel<<<B, 128, 0, stream>>>(pooledp, W, bias, out);
    } else if (ws_size >= emb_flat_bytes) {
        unsigned short* embb = (unsigned short*)d_ws;
        convert_flat_kernel<<<(VOCAB * D / 4) / 256, 256, 0, stream>>>(emb, embb);
        pool_gemm_bf16_kernel<<<B, 256, 0, stream>>>(diag, proc, embb, W, bias, out);
    } else {
        pool_gemm_f32_kernel<<<B, 256, 0, stream>>>(diag, proc, emb, W, bias, out);
    }
}